// Round 7
// baseline (25519.467 us; speedup 1.0000x reference)
//
#include <hip/hip_runtime.h>

// Problem constants
constexpr int BB   = 64;     // batch
constexpr int HH   = 256;    // hidden (H)
constexpr int PP   = 128;    // prenet out
constexpr int MM   = 512;    // memory length
constexpr int NM   = 80;     // num mels
constexpr int RR   = 5;      // outputs per step
constexpr int TIN  = 2000;   // input time
constexpr int NSTEP= 400;    // decoder steps

__device__ __forceinline__ float sigf(float x)  { return 1.0f / (1.0f + __expf(-x)); }
__device__ __forceinline__ float tanhfast(float x) { return 1.0f - 2.0f / (1.0f + __expf(2.0f * x)); }
__device__ __forceinline__ unsigned short bf16rne(float x) {
  unsigned int u = __float_as_uint(x);
  u += 0x7fffu + ((u >> 16) & 1u);
  return (unsigned short)(u >> 16);
}
__device__ __forceinline__ unsigned packbf(float a, float b) {
  return (unsigned)bf16rne(a) | ((unsigned)bf16rne(b) << 16);
}
__device__ __forceinline__ float2 unpk(unsigned u) {
  float2 r;
  r.x = __uint_as_float(u << 16);
  r.y = __uint_as_float(u & 0xffff0000u);
  return r;
}
// 8 MACs from one uint4 (8 packed bf16 weights) against LDS vector x[k0..k0+7]
__device__ __forceinline__ void mac8(float& acc, uint4 q, const float* __restrict__ x, int k0) {
  float2 f0 = unpk(q.x), f1 = unpk(q.y), f2 = unpk(q.z), f3 = unpk(q.w);
  acc += f0.x * x[k0]     + f0.y * x[k0 + 1]
       + f1.x * x[k0 + 2] + f1.y * x[k0 + 3]
       + f2.x * x[k0 + 4] + f2.y * x[k0 + 5]
       + f3.x * x[k0 + 6] + f3.y * x[k0 + 7];
}

// ---------------- prenet: only the 400 consumed frames ----------------
__global__ void __launch_bounds__(128) prenet_kernel(
    const float* __restrict__ din, const float* __restrict__ fc1w, const float* __restrict__ fc1b,
    const float* __restrict__ fc2w, const float* __restrict__ fc2b, float* __restrict__ tf) {
  int t = blockIdx.x, b = blockIdx.y, tid = threadIdx.x;
  __shared__ float x[NM];
  __shared__ float h1[256];
  if (tid < NM) x[tid] = din[(size_t)b * NM * TIN + (size_t)tid * TIN + t * RR];
  __syncthreads();
  for (int o = tid; o < 256; o += 128) {
    float a = fc1b[o];
    const float* w = fc1w + o * NM;
    for (int k = 0; k < NM; ++k) a += x[k] * w[k];
    h1[o] = fmaxf(a, 0.f);
  }
  __syncthreads();
  {
    int o = tid;
    float a = fc2b[o];
    const float* w = fc2w + o * 256;
    for (int k = 0; k < 256; ++k) a += h1[k] * w[k];
    tf[((size_t)t * BB + b) * PP + o] = fmaxf(a, 0.f);
  }
}

// ---- pack chunked-transposed: src fp32 [O][K] -> dst uint4 [K/8][O]; one uint4 = k..k+7 ----
__global__ void __launch_bounds__(256) packC4_kernel(
    const float* __restrict__ src, uint4* __restrict__ dst, int O, int K) {
  int K8 = K >> 3;
  int idx = blockIdx.x * 256 + threadIdx.x;
  if (idx >= O * K8) return;
  int o = idx % O, k8 = idx / O;
  const float* s = src + (size_t)o * K + 8 * k8;
  uint4 q;
  q.x = packbf(s[0], s[1]); q.y = packbf(s[2], s[3]);
  q.z = packbf(s[4], s[5]); q.w = packbf(s[6], s[7]);
  dst[(size_t)k8 * O + o] = q;
}

// ---------------- memB2: mem fp32 [b][m][h] -> uint [b][m][h/2] ----------------
__global__ void __launch_bounds__(256) packMem_kernel(
    const float* __restrict__ mem, unsigned* __restrict__ memB2) {
  int idx = blockIdx.x * 256 + threadIdx.x;   // over BB*MM*128
  if (idx >= BB * MM * 128) return;
  memB2[idx] = packbf(mem[2 * (size_t)idx], mem[2 * (size_t)idx + 1]);
}

// ---- key2C: keys chunked: uint4 [b][hpc=h/8][m], one uint4 = h=8hpc..8hpc+7 at col m ----
__global__ void __launch_bounds__(256) keys2_kernel(
    const float* __restrict__ mem, const float* __restrict__ W1, uint4* __restrict__ key2C) {
  int blk = blockIdx.x;
  int b = blk >> 6, mc = blk & 63, m0 = mc * 8, tid = threadIdx.x;
  __shared__ float sm[2048];
  for (int i = tid; i < 2048; i += 256)
    sm[i] = mem[((size_t)b * MM + m0 + (i >> 8)) * HH + (i & 255)];
  __syncthreads();
  float acc[8] = {0, 0, 0, 0, 0, 0, 0, 0};
  const float* w = W1 + (size_t)tid * 256;
  for (int k = 0; k < 256; ++k) {
    float wk = w[k];
#pragma unroll
    for (int r = 0; r < 8; ++r) acc[r] += sm[r * 256 + k] * wk;
  }
  __syncthreads();   // all reads of sm done
#pragma unroll
  for (int r = 0; r < 8; ++r) sm[tid * 8 + r] = acc[r];   // sm[h][r], h = tid
  __syncthreads();
  {
    int hpc = tid >> 3, r = tid & 7;      // 32 h-chunks x 8 m
    int h0 = hpc * 8;
    uint4 q;
    q.x = packbf(sm[(h0 + 0) * 8 + r], sm[(h0 + 1) * 8 + r]);
    q.y = packbf(sm[(h0 + 2) * 8 + r], sm[(h0 + 3) * 8 + r]);
    q.z = packbf(sm[(h0 + 4) * 8 + r], sm[(h0 + 5) * 8 + r]);
    q.w = packbf(sm[(h0 + 6) * 8 + r], sm[(h0 + 7) * 8 + r]);
    key2C[((size_t)b * 32 + hpc) * 512 + m0 + r] = q;
  }
}

// ---------------- the per-batch-element decoder: 1 block = 1 b ----------------
struct DP {
  const float *tf;
  const uint4 *W2C, *projC, *outC;
  const uint4 *awihC, *awhhC, *g1wihC, *g1whhC, *g2wihC, *g2whhC;
  const uint4 *key2C;
  const unsigned *memB2;
  const float *a_bih, *a_bhh, *g1_bih, *g1_bhh, *g2_bih, *g2_bhh;
  const float *proj_b, *out_b, *v;
  float *out;
};

// bias LDS layout offsets
//   0    a_bih[768]   768  a_bhh[768]
//   1536 g1_bih[768]  2304 g1_bhh[768]
//   3072 g2_bih[768]  3840 g2_bhh[768]
//   4608 proj_b[256]  4864 out_b[400]  5264 v[256]   total 5520
__global__ void __launch_bounds__(1024) decoder64(DP p) {
  const int b = blockIdx.x, tid = threadIdx.x;
  const int lane = tid & 63, wid = tid >> 6;
  __shared__ float d_s[256], xf[128], w2dv[256], sc[512], ctxv[256];
  __shared__ float g1inv[256], g2inv[256], g1h[256], g2h[256], bfv[256];
  __shared__ float gbuf[1536], red[2048], wredA[16], wredB[16];
  __shared__ float bias[5520];

  if (tid < 768) {
    bias[tid]        = p.a_bih[tid];  bias[768 + tid]  = p.a_bhh[tid];
    bias[1536 + tid] = p.g1_bih[tid]; bias[2304 + tid] = p.g1_bhh[tid];
    bias[3072 + tid] = p.g2_bih[tid]; bias[3840 + tid] = p.g2_bhh[tid];
  }
  if (tid < 256) { bias[4608 + tid] = p.proj_b[tid]; bias[5264 + tid] = p.v[tid]; }
  if (tid < 400) bias[4864 + tid] = p.out_b[tid];
  if (tid < 256) { d_s[tid] = 0.f; g1h[tid] = 0.f; g2h[tid] = 0.f; }
  __syncthreads();

  for (int t = 0; t < NSTEP; ++t) {
    // --- Phase A: attention GRU  d = GRU(x_t, d) ---
    if (tid < 128) xf[tid] = p.tf[((size_t)t * BB + b) * PP + tid];
    __syncthreads();
    if (tid < 768) {
      float acc = 0.f, acc2 = 0.f;
      const uint4* w = p.awihC + tid;   // [16][768]
      const uint4* u = p.awhhC + tid;   // [32][768]
#pragma unroll 4
      for (int c = 0; c < 16; ++c) mac8(acc, w[(size_t)c * 768], xf, c * 8);
#pragma unroll 4
      for (int c = 0; c < 32; ++c) mac8(acc2, u[(size_t)c * 768], d_s, c * 8);
      gbuf[tid] = acc; gbuf[768 + tid] = acc2;
    }
    __syncthreads();
    if (tid < 256) {
      int h = tid;
      float r = sigf(gbuf[h]       + bias[h]       + gbuf[768 + h]  + bias[768 + h]);
      float z = sigf(gbuf[256 + h] + bias[256 + h] + gbuf[1024 + h] + bias[1024 + h]);
      float n = tanhfast(gbuf[512 + h] + bias[512 + h] + r * (gbuf[1280 + h] + bias[1280 + h]));
      d_s[h] = (1.f - z) * n + z * d_s[h];
    }
    __syncthreads();

    // --- Phase B: w2d = W2 @ d   (W2C uint4 [32][256], kp covers 8 chunks each) ---
    {
      int o = tid & 255, kp = tid >> 8;
      const uint4* w = p.W2C + (size_t)(kp * 8) * 256 + o;
      float acc = 0.f;
#pragma unroll 4
      for (int c = 0; c < 8; ++c) mac8(acc, w[(size_t)c * 256], d_s, (kp * 8 + c) * 8);
      red[tid] = acc;
    }
    __syncthreads();
    if (tid < 256) w2dv[tid] = red[tid] + red[256 + tid] + red[512 + tid] + red[768 + tid];
    __syncthreads();

    // --- Phase C: scores[m] = sum_h v[h] * tanh(keys[b][h][m] + w2d[h])  (key2C uint4) ---
    {
      int m = tid & 511, kp = tid >> 9;   // kp in {0,1}: 16 h-chunks each
      const uint4* kq = p.key2C + ((size_t)b * 32 + kp * 16) * 512 + m;
      float acc = 0.f;
#pragma unroll 4
      for (int c = 0; c < 16; ++c) {
        uint4 q = kq[(size_t)c * 512];
        int h0 = (kp * 16 + c) * 8;
        float2 f0 = unpk(q.x), f1 = unpk(q.y), f2 = unpk(q.z), f3 = unpk(q.w);
        acc += bias[5264 + h0 + 0] * tanhfast(f0.x + w2dv[h0 + 0])
             + bias[5264 + h0 + 1] * tanhfast(f0.y + w2dv[h0 + 1])
             + bias[5264 + h0 + 2] * tanhfast(f1.x + w2dv[h0 + 2])
             + bias[5264 + h0 + 3] * tanhfast(f1.y + w2dv[h0 + 3])
             + bias[5264 + h0 + 4] * tanhfast(f2.x + w2dv[h0 + 4])
             + bias[5264 + h0 + 5] * tanhfast(f2.y + w2dv[h0 + 5])
             + bias[5264 + h0 + 6] * tanhfast(f3.x + w2dv[h0 + 6])
             + bias[5264 + h0 + 7] * tanhfast(f3.y + w2dv[h0 + 7]);
      }
      red[tid] = acc;
    }
    __syncthreads();
    if (tid < 512) sc[tid] = red[tid] + red[512 + tid];
    __syncthreads();

    // --- Phase D: softmax over 512 ---
    {
      float s = (tid < 512) ? sc[tid] : -1e30f;
      float mx = s;
      for (int off = 32; off; off >>= 1) mx = fmaxf(mx, __shfl_xor(mx, off));
      if (lane == 0) wredA[wid] = mx;
      __syncthreads();
      float gmax = wredA[0];
      for (int i = 1; i < 16; ++i) gmax = fmaxf(gmax, wredA[i]);
      float e = (tid < 512) ? __expf(s - gmax) : 0.f;
      float sum = e;
      for (int off = 32; off; off >>= 1) sum += __shfl_xor(sum, off);
      if (lane == 0) wredB[wid] = sum;
      __syncthreads();
      float gsum = 0.f;
      for (int i = 0; i < 16; ++i) gsum += wredB[i];
      if (tid < 512) sc[tid] = e / gsum;
    }
    __syncthreads();

    // --- Phase E: ctx[h] = sum_m attw[m] * mem[b][m][h]  (memB2 uint [b][m][128]) ---
    {
      int hp = tid & 127, mp = tid >> 7;   // mp in [0,8): 64 m each
      const unsigned* mb = p.memB2 + ((size_t)b * MM + mp * 64) * 128 + hp;
      float acc0 = 0.f, acc1 = 0.f;
#pragma unroll 16
      for (int m = 0; m < 64; ++m) {
        float2 f = unpk(mb[(size_t)m * 128]);
        float wgt = sc[mp * 64 + m];
        acc0 += wgt * f.x; acc1 += wgt * f.y;
      }
      red[mp * 256 + 2 * hp] = acc0;
      red[mp * 256 + 2 * hp + 1] = acc1;
    }
    __syncthreads();
    if (tid < 256) {
      float a = 0.f;
#pragma unroll
      for (int mp = 0; mp < 8; ++mp) a += red[mp * 256 + tid];
      ctxv[tid] = a;
    }
    __syncthreads();

    // --- Phase F: g1in = proj @ concat(d, ctx) + proj_b  (projC uint4 [64][256]) ---
    {
      int o = tid & 255, q4 = tid >> 8;    // q4 in [0,4): 16 chunks each
      const uint4* w = p.projC + (size_t)(q4 * 16) * 256 + o;
      const float* u = (q4 < 2) ? d_s : ctxv;
      float acc = 0.f;
#pragma unroll 4
      for (int c = 0; c < 16; ++c) mac8(acc, w[(size_t)c * 256], u, ((q4 & 1) * 16 + c) * 8);
      red[tid] = acc;
    }
    __syncthreads();
    if (tid < 256) g1inv[tid] = red[tid] + red[256 + tid] + red[512 + tid] + red[768 + tid] + bias[4608 + tid];
    __syncthreads();

    // --- Phase G: GRU1; g2in = g1in + g1h  (uint4 [32][768] each) ---
    if (tid < 768) {
      float acc = 0.f, acc2 = 0.f;
      const uint4* w = p.g1wihC + tid;
      const uint4* u = p.g1whhC + tid;
#pragma unroll 4
      for (int c = 0; c < 32; ++c) {
        mac8(acc,  w[(size_t)c * 768], g1inv, c * 8);
        mac8(acc2, u[(size_t)c * 768], g1h,   c * 8);
      }
      gbuf[tid] = acc; gbuf[768 + tid] = acc2;
    }
    __syncthreads();
    if (tid < 256) {
      int h = tid;
      float r = sigf(gbuf[h]       + bias[1536 + h] + gbuf[768 + h]  + bias[2304 + h]);
      float z = sigf(gbuf[256 + h] + bias[1792 + h] + gbuf[1024 + h] + bias[2560 + h]);
      float n = tanhfast(gbuf[512 + h] + bias[2048 + h] + r * (gbuf[1280 + h] + bias[2816 + h]));
      float nh = (1.f - z) * n + z * g1h[h];
      g1h[h] = nh;
      g2inv[h] = g1inv[h] + nh;
    }
    __syncthreads();

    // --- Phase H: GRU2; bf = g2in + g2h ---
    if (tid < 768) {
      float acc = 0.f, acc2 = 0.f;
      const uint4* w = p.g2wihC + tid;
      const uint4* u = p.g2whhC + tid;
#pragma unroll 4
      for (int c = 0; c < 32; ++c) {
        mac8(acc,  w[(size_t)c * 768], g2inv, c * 8);
        mac8(acc2, u[(size_t)c * 768], g2h,   c * 8);
      }
      gbuf[tid] = acc; gbuf[768 + tid] = acc2;
    }
    __syncthreads();
    if (tid < 256) {
      int h = tid;
      float r = sigf(gbuf[h]       + bias[3072 + h] + gbuf[768 + h]  + bias[3840 + h]);
      float z = sigf(gbuf[256 + h] + bias[3328 + h] + gbuf[1024 + h] + bias[4096 + h]);
      float n = tanhfast(gbuf[512 + h] + bias[3584 + h] + r * (gbuf[1280 + h] + bias[4352 + h]));
      float nh = (1.f - z) * n + z * g2h[h];
      g2h[h] = nh;
      bfv[h] = g2inv[h] + nh;
    }
    __syncthreads();

    // --- Phase I: out = out_w @ bf + out_b  (outC uint4 [32][400]) ---
    if (tid < 800) {
      int j  = (tid < 400) ? tid : tid - 400;
      int kp = (tid < 400) ? 0 : 1;
      const uint4* w = p.outC + (size_t)(kp * 16) * 400 + j;
      float acc = 0.f;
#pragma unroll 4
      for (int c = 0; c < 16; ++c) mac8(acc, w[(size_t)c * 400], bfv, (kp * 16 + c) * 8);
      red[tid] = acc;
    }
    __syncthreads();
    if (tid < 400) {
      float a = red[tid] + red[400 + tid] + bias[4864 + tid];
      int mel = tid / 5, r = tid - mel * 5;
      p.out[(size_t)b * NM * TIN + (size_t)mel * TIN + t * RR + r] = a;
    }
    __syncthreads();
  }
}

extern "C" void kernel_launch(void* const* d_in, const int* in_sizes, int n_in,
                              void* d_out, int out_size, void* d_ws, size_t ws_size,
                              hipStream_t stream) {
  const float* din    = (const float*)d_in[0];
  const float* mem    = (const float*)d_in[1];
  const float* fc1w   = (const float*)d_in[2];
  const float* fc1b   = (const float*)d_in[3];
  const float* fc2w   = (const float*)d_in[4];
  const float* fc2b   = (const float*)d_in[5];
  const float* W1     = (const float*)d_in[6];
  const float* W2     = (const float*)d_in[7];
  const float* vw     = (const float*)d_in[8];
  const float* a_wih  = (const float*)d_in[9];
  const float* a_whh  = (const float*)d_in[10];
  const float* a_bih  = (const float*)d_in[11];
  const float* a_bhh  = (const float*)d_in[12];
  const float* g1_wih = (const float*)d_in[13];
  const float* g1_whh = (const float*)d_in[14];
  const float* g1_bih = (const float*)d_in[15];
  const float* g1_bhh = (const float*)d_in[16];
  const float* g2_wih = (const float*)d_in[17];
  const float* g2_whh = (const float*)d_in[18];
  const float* g2_bih = (const float*)d_in[19];
  const float* g2_bhh = (const float*)d_in[20];
  const float* proj_w = (const float*)d_in[21];
  const float* proj_b = (const float*)d_in[22];
  const float* out_w  = (const float*)d_in[23];
  const float* out_b  = (const float*)d_in[24];

  float* ws = (float*)d_ws;
  size_t o = 0;
  float* tf = ws + o;                   o += (size_t)NSTEP * BB * PP;     // 3,276,800 f (div 4)
  uint4* W2C    = (uint4*)(ws + o); o += 256 * 256 / 2;    // uints == floats count
  uint4* projC  = (uint4*)(ws + o); o += 256 * 512 / 2;
  uint4* outC   = (uint4*)(ws + o); o += 400 * 256 / 2;
  uint4* awihC  = (uint4*)(ws + o); o += 768 * 128 / 2;
  uint4* awhhC  = (uint4*)(ws + o); o += 768 * 256 / 2;
  uint4* g1wihC = (uint4*)(ws + o); o += 768 * 256 / 2;
  uint4* g1whhC = (uint4*)(ws + o); o += 768 * 256 / 2;
  uint4* g2wihC = (uint4*)(ws + o); o += 768 * 256 / 2;
  uint4* g2whhC = (uint4*)(ws + o); o += 768 * 256 / 2;
  uint4* key2C  = (uint4*)(ws + o); o += (size_t)BB * 128 * MM;   // 4,194,304 uints
  unsigned* memB2 = (unsigned*)(ws + o); o += (size_t)BB * MM * 128;

  prenet_kernel<<<dim3(NSTEP, BB), 128, 0, stream>>>(din, fc1w, fc1b, fc2w, fc2b, tf);

  auto packC = [&](const float* src, uint4* dst, int O, int K) {
    int n = O * (K / 8);
    packC4_kernel<<<(n + 255) / 256, 256, 0, stream>>>(src, dst, O, K);
  };
  packC(W2,     W2C,    256, 256);
  packC(proj_w, projC,  256, 512);
  packC(out_w,  outC,   400, 256);
  packC(a_wih,  awihC,  768, 128);
  packC(a_whh,  awhhC,  768, 256);
  packC(g1_wih, g1wihC, 768, 256);
  packC(g1_whh, g1whhC, 768, 256);
  packC(g2_wih, g2wihC, 768, 256);
  packC(g2_whh, g2whhC, 768, 256);

  packMem_kernel<<<(BB * MM * 128 + 255) / 256, 256, 0, stream>>>(mem, memB2);
  keys2_kernel<<<4096, 256, 0, stream>>>(mem, W1, key2C);

  DP p;
  p.tf = tf;
  p.W2C = W2C; p.projC = projC; p.outC = outC;
  p.awihC = awihC; p.awhhC = awhhC;
  p.g1wihC = g1wihC; p.g1whhC = g1whhC; p.g2wihC = g2wihC; p.g2whhC = g2whhC;
  p.key2C = key2C; p.memB2 = memB2;
  p.a_bih = a_bih; p.a_bhh = a_bhh; p.g1_bih = g1_bih; p.g1_bhh = g1_bhh;
  p.g2_bih = g2_bih; p.g2_bhh = g2_bhh;
  p.proj_b = proj_b; p.out_b = out_b; p.v = vw;
  p.out = (float*)d_out;

  decoder64<<<BB, 1024, 0, stream>>>(p);
}